// Round 15
// baseline (460.661 us; speedup 1.0000x reference)
//
#include <hip/hip_runtime.h>

// Problem constants
#define N_ROWS 32768   // 8*4096
#define DIM    256
#define KCODES 8192
#define DECAYF 0.8f
#define OMDF   0.2f
#define EPSF   1e-5f

// d_out layout (float element offsets)
#define Q_OFF    0
#define IND_OFF  8388608
#define CS_OFF   8421376
#define EA_OFF   8429568
#define NE_OFF   10526720

// Scratch: Xp -> Q first half; rowlist -> Q second half; gbest -> EA head;
// Ep -> EA + 65536 floats. Same proven placement as r10-r14.

// ws layout: e2 f32[8192], cnt i32[8192], start i32[8192], cursor i32[8192],
// sum f32[1]
#define WS_E2    0
#define WS_CNT   8192
#define WS_START 16384
#define WS_CUR   24576
#define WS_SUM   40960

typedef _Float16 half8 __attribute__((ext_vector_type(8)));
typedef float floatx4 __attribute__((ext_vector_type(4)));

#define GLOAD16(g, l) __builtin_amdgcn_global_load_lds( \
    (const __attribute__((address_space(1))) void*)(g), \
    (__attribute__((address_space(3))) void*)(l), 16, 0, 0)

// ---------------------------------------------------------------------------
// prep_all (r10-verified, unchanged)
#define PREP_ROWS 32
__global__ void prep_all_kernel(const float* __restrict__ x,
                                const float* __restrict__ embed,
                                const float* __restrict__ cs,
                                _Float16* __restrict__ Xp,
                                _Float16* __restrict__ Ep,
                                float* __restrict__ out,
                                float* __restrict__ ws) {
  __shared__ __align__(16) _Float16 L[PREP_ROWS][264];
  __shared__ float red[4];
  const int t = threadIdx.x;
  const int bid = blockIdx.x;

  if (bid < 1024) {
    if (bid < 128) {
      unsigned long long* gbest = (unsigned long long*)(out + EA_OFF);
      gbest[bid * 256 + t] = 0ULL;
    } else if (bid < 160) {
      ((int*)(ws + WS_CNT))[(bid - 128) * 256 + t] = 0;
    }
    const int row0 = bid * PREP_ROWS;
    #pragma unroll
    for (int it = 0; it < 8; ++it) {
      int idx = it * 256 + t;
      int r = idx >> 6, q = idx & 63;
      float4 v = *(const float4*)&x[(size_t)(row0 + r) * DIM + q * 4];
      L[r][q * 4 + 0] = (_Float16)v.x;
      L[r][q * 4 + 1] = (_Float16)v.y;
      L[r][q * 4 + 2] = (_Float16)v.z;
      L[r][q * 4 + 3] = (_Float16)v.w;
    }
    __syncthreads();
    #pragma unroll
    for (int it = 0; it < 4; ++it) {
      int idx = it * 256 + t;
      int slot = idx >> 5, r = idx & 31;
      *(float4*)&Xp[((size_t)slot * N_ROWS + row0 + r) * 8] =
          *(const float4*)&L[r][slot * 8];
    }
  } else {
    const int row0 = (bid - 1024) * PREP_ROWS;
    float* e2 = ws + WS_E2;
    #pragma unroll
    for (int it = 0; it < 8; ++it) {
      int idx = it * 256 + t;
      int r = idx >> 6, q = idx & 63;
      float4 v = *(const float4*)&embed[(size_t)(row0 + r) * DIM + q * 4];
      L[r][q * 4 + 0] = (_Float16)v.x;
      L[r][q * 4 + 1] = (_Float16)v.y;
      L[r][q * 4 + 2] = (_Float16)v.z;
      L[r][q * 4 + 3] = (_Float16)v.w;
      float ssq = v.x * v.x + v.y * v.y + v.z * v.z + v.w * v.w;
      #pragma unroll
      for (int o = 32; o; o >>= 1) ssq += __shfl_xor(ssq, o);
      if ((t & 63) == 0) e2[row0 + r] = ssq;
    }
    if (bid == 1024) {
      float s = 0.0f;
      for (int j = t; j < KCODES; j += 256) s += cs[j];
      #pragma unroll
      for (int o = 32; o; o >>= 1) s += __shfl_xor(s, o);
      if ((t & 63) == 0) red[t >> 6] = s;
    }
    __syncthreads();
    if (bid == 1024 && t == 0)
      ws[WS_SUM] = red[0] + red[1] + red[2] + red[3];
    #pragma unroll
    for (int it = 0; it < 4; ++it) {
      int idx = it * 256 + t;
      int slot = idx >> 5, r = idx & 31;
      *(float4*)&Ep[((size_t)slot * KCODES + row0 + r) * 8] =
          *(const float4*)&L[r][slot * 8];
    }
  }
}

// ---------------------------------------------------------------------------
// Main MFMA kernel — m201-style phase schedule at 16x16x32_f16.
// Block 256 codes x 256 rows, 8 waves (2Mx4N), wave tile 128x64 = 8x4 frags.
// Per K32-step: 2 phases x 16 independent MFMAs, each phase
// {ds-reads || 2 gloads -> barrier -> lgkm(0) -> 16 MFMA -> barrier};
// counted vmcnt(4) once per step. Persistent 16 row-tiles per block
// (256 blocks = 1/CU), per-tile argmax flush + vmcnt(0) re-prime.
__global__ __launch_bounds__(512, 2) void main_kernel(
    const _Float16* __restrict__ Xp, const _Float16* __restrict__ Ep,
    const float* __restrict__ e2, unsigned long long* __restrict__ gbest) {
  __shared__ __align__(16) _Float16 As[4 * 4 * 256 * 8];  // [buf][slot][code][8] 64KB
  __shared__ __align__(16) _Float16 Bs[4 * 4 * 256 * 8];  // [buf][slot][row][8]  64KB
  __shared__ __align__(16) float e2s[256];                // 1KB

  const int t = threadIdx.x;
  const int w = t >> 6;
  const int lane = t & 63;
  const int l15 = lane & 15;
  const int g4 = lane >> 4;   // k-group 0..3 (8 k's each within a K32)
  const int wm = w >> 2;      // code half 0..1
  const int wn = w & 3;       // row quarter 0..3

  const int bid = blockIdx.x;
  const int bi = bid >> 3;                   // 0..31
  const int cb = (bid & 7) * 4 + (bi >> 3);  // 0..31
  const int rbg = bi & 7;                    // 0..7
  const int codes0 = cb * 256;
  const int rowbase = rbg * 4096;            // 16 row-tiles of 256

  const bool isA = (w < 4);
  const int slot = isA ? w : (w - 4);

  const _Float16* estage = Ep + ((size_t)slot * KCODES + codes0 + lane) * 8;
  const _Float16* xstage = Xp + ((size_t)slot * N_ROWS + rowbase + lane) * 8;
  _Float16* adst = &As[slot * 2048];
  _Float16* bdst = &Bs[slot * 2048];

  // stage half a K32-step's panel: 2 gloads (q0, q0+1)
  auto stage2 = [&](int buf, int se4, int rowT, int q0) {
    if (isA) {
      const _Float16* src = estage + (size_t)se4 * (KCODES * 8);
      _Float16* dst = adst + buf * 8192;
      GLOAD16(src + q0 * 512, dst + q0 * 512);
      GLOAD16(src + (q0 + 1) * 512, dst + (q0 + 1) * 512);
    } else {
      const _Float16* src =
          xstage + (size_t)se4 * (N_ROWS * 8) + (size_t)rowT * 2048;
      _Float16* dst = bdst + buf * 8192;
      GLOAD16(src + q0 * 512, dst + q0 * 512);
      GLOAD16(src + (q0 + 1) * 512, dst + (q0 + 1) * 512);
    }
  };

  if (t < 64) {
    float4 v = *(const float4*)&e2[codes0 + t * 4];
    *(float4*)&e2s[t * 4] = v;
  }
  __builtin_amdgcn_sched_barrier(0);
  stage2(0, 0, 0, 0); stage2(0, 0, 0, 2);
  stage2(1, 4, 0, 0); stage2(1, 4, 0, 2);
  asm volatile("s_waitcnt vmcnt(4)" ::: "memory");
  asm volatile("s_waitcnt lgkmcnt(0)" ::: "memory");
  __builtin_amdgcn_s_barrier();
  __builtin_amdgcn_sched_barrier(0);

  floatx4 acc[8][4];

  #pragma unroll 1
  for (int sg = 0; sg < 4; ++sg) {
    #pragma unroll
    for (int tt = 0; tt < 4; ++tt) {
      const int rowT = sg * 4 + tt;
      // acc init = -0.5*e2 (broadcast LDS reads; lgkm domain)
      #pragma unroll
      for (int mf = 0; mf < 8; ++mf) {
        float4 v = *(const float4*)&e2s[wm * 128 + mf * 16 + g4 * 4];
        floatx4 a;
        a[0] = -0.5f * v.x; a[1] = -0.5f * v.y;
        a[2] = -0.5f * v.z; a[3] = -0.5f * v.w;
        acc[mf][0] = a; acc[mf][1] = a; acc[mf][2] = a; acc[mf][3] = a;
      }
      __builtin_amdgcn_sched_barrier(0);

      #pragma unroll
      for (int i = 0; i < 8; ++i) {
        const bool lastTile = (sg == 3) && (tt == 3);
        const bool doStage = !(lastTile && i >= 6);
        const int buf = i & 3;
        const int abase = buf * 8192 + g4 * 2048 + (wm * 128 + l15) * 8;
        const int bbase = buf * 8192 + g4 * 2048 + (wn * 64 + l15) * 8;
        const int sbuf = (i + 2) & 3;
        const int sse4 = ((i + 2) & 7) * 4;
        const int srow = rowT + ((i + 2) >> 3);

        // ---- phase 0: all B frags + A mf 0..3; stage halves q0,q1
        half8 bf[4], af[4];
        #pragma unroll
        for (int nf = 0; nf < 4; ++nf)
          bf[nf] = *(const half8*)&Bs[bbase + nf * 128];
        #pragma unroll
        for (int mf = 0; mf < 4; ++mf)
          af[mf] = *(const half8*)&As[abase + mf * 128];
        if (doStage) stage2(sbuf, sse4, srow, 0);
        __builtin_amdgcn_sched_barrier(0);
        __builtin_amdgcn_s_barrier();
        asm volatile("s_waitcnt lgkmcnt(0)" ::: "memory");
        __builtin_amdgcn_sched_barrier(0);
        __builtin_amdgcn_s_setprio(1);
        #pragma unroll
        for (int mf = 0; mf < 4; ++mf)
          #pragma unroll
          for (int nf = 0; nf < 4; ++nf)
            acc[mf][nf] = __builtin_amdgcn_mfma_f32_16x16x32_f16(
                af[mf], bf[nf], acc[mf][nf], 0, 0, 0);
        __builtin_amdgcn_s_setprio(0);
        __builtin_amdgcn_sched_barrier(0);
        __builtin_amdgcn_s_barrier();

        // ---- phase 1: A mf 4..7; stage halves q2,q3
        #pragma unroll
        for (int mf = 0; mf < 4; ++mf)
          af[mf] = *(const half8*)&As[abase + (64 + mf * 16) * 8];
        if (doStage) stage2(sbuf, sse4, srow, 2);
        __builtin_amdgcn_sched_barrier(0);
        __builtin_amdgcn_s_barrier();
        asm volatile("s_waitcnt lgkmcnt(0)" ::: "memory");
        __builtin_amdgcn_sched_barrier(0);
        __builtin_amdgcn_s_setprio(1);
        #pragma unroll
        for (int mf = 0; mf < 4; ++mf)
          #pragma unroll
          for (int nf = 0; nf < 4; ++nf)
            acc[4 + mf][nf] = __builtin_amdgcn_mfma_f32_16x16x32_f16(
                af[mf], bf[nf], acc[4 + mf][nf], 0, 0, 0);
        __builtin_amdgcn_s_setprio(0);
        __builtin_amdgcn_sched_barrier(0);
        if (!(lastTile && i == 7)) {
          if (!(lastTile && i == 6)) {
            asm volatile("s_waitcnt vmcnt(4)" ::: "memory");
          } else {
            asm volatile("s_waitcnt vmcnt(0)" ::: "memory");
          }
          __builtin_amdgcn_s_barrier();
        }
        __builtin_amdgcn_sched_barrier(0);
      }

      // tile epilogue: per-nf lane argmax -> g4-group butterfly -> atomicMax
      // C layout (16x16): col(xrow)=lane&15, row(code)=g4*4+reg [m89/m91]
      #pragma unroll
      for (int nf = 0; nf < 4; ++nf) {
        float best = -3.0e38f;
        int bidx = 0;
        #pragma unroll
        for (int mf = 0; mf < 8; ++mf) {
          const int cbase = codes0 + wm * 128 + mf * 16 + g4 * 4;
          #pragma unroll
          for (int r = 0; r < 4; ++r) {
            float v = acc[mf][nf][r];
            const int code = cbase + r;
            if (v > best || (v == best && code < bidx)) { best = v; bidx = code; }
          }
        }
        unsigned u = __float_as_uint(best);
        u = (u & 0x80000000u) ? ~u : (u | 0x80000000u);
        unsigned long long p =
            ((unsigned long long)u << 32) | (unsigned)(8191 - bidx);
        unsigned long long op = (unsigned long long)__shfl_xor((long long)p, 16);
        if (op > p) p = op;
        op = (unsigned long long)__shfl_xor((long long)p, 32);
        if (op > p) p = op;
        if (g4 == 0)
          atomicMax(&gbest[rowbase + rowT * 256 + wn * 64 + nf * 16 + l15], p);
      }
      if (!(sg == 3 && tt == 3)) {
        asm volatile("s_waitcnt vmcnt(0)" ::: "memory");  // re-prime rhythm
        __builtin_amdgcn_sched_barrier(0);
      }
    }
  }
}

// ---------------------------------------------------------------------------
// decode_count: gbest -> IND + cnt histogram. Last reader of gbest.
__global__ void decode_count_kernel(const unsigned long long* __restrict__ gbest,
                                    float* __restrict__ out,
                                    int* __restrict__ cnt) {
  int r = blockIdx.x * blockDim.x + threadIdx.x;  // 32768 threads
  unsigned long long p = gbest[r];
  int k = 8191 - (int)(unsigned)(p & 0xFFFFFFFFull);
  out[IND_OFF + r] = (float)k;
  atomicAdd(&cnt[k], 1);
}

// ---------------------------------------------------------------------------
__global__ void prefix_kernel(const int* __restrict__ cnt,
                              int* __restrict__ start,
                              int* __restrict__ cursor) {
  __shared__ int part[1024];
  const int t = threadIdx.x;
  int loc[8];
  int s = 0;
  #pragma unroll
  for (int j = 0; j < 8; ++j) { loc[j] = cnt[t * 8 + j]; s += loc[j]; }
  part[t] = s;
  __syncthreads();
  for (int off = 1; off < 1024; off <<= 1) {
    int v = (t >= off) ? part[t - off] : 0;
    __syncthreads();
    part[t] += v;
    __syncthreads();
  }
  int base = part[t] - s;
  #pragma unroll
  for (int j = 0; j < 8; ++j) {
    start[t * 8 + j] = base;
    cursor[t * 8 + j] = base;
    base += loc[j];
  }
}

// ---------------------------------------------------------------------------
__global__ void scatter_rows_kernel(const float* __restrict__ out,
                                    int* __restrict__ cursor,
                                    int* __restrict__ rowlist) {
  int r = blockIdx.x * blockDim.x + threadIdx.x;  // 32768 threads
  int k = (int)out[IND_OFF + r];
  int pos = atomicAdd(&cursor[k], 1);
  rowlist[pos] = r;
}

// ---------------------------------------------------------------------------
__global__ void bucket_final_kernel(const float* __restrict__ x,
                                    const float* __restrict__ cs,
                                    const float* __restrict__ embed_avg,
                                    const int* __restrict__ start,
                                    const int* __restrict__ cnt,
                                    const int* __restrict__ rowlist,
                                    float* __restrict__ out,
                                    const float* __restrict__ ws_sum) {
  const int lane = threadIdx.x & 63;
  const int k = blockIdx.x * 4 + (threadIdx.x >> 6);
  const int s = start[k];
  const int n = cnt[k];
  float4 acc = make_float4(0.f, 0.f, 0.f, 0.f);
  int i = 0;
  for (; i + 2 <= n; i += 2) {
    int r0 = rowlist[s + i];
    int r1 = rowlist[s + i + 1];
    float4 v0 = *(const float4*)&x[(size_t)r0 * DIM + lane * 4];
    float4 v1 = *(const float4*)&x[(size_t)r1 * DIM + lane * 4];
    acc.x += v0.x + v1.x; acc.y += v0.y + v1.y;
    acc.z += v0.z + v1.z; acc.w += v0.w + v1.w;
  }
  if (i < n) {
    int r0 = rowlist[s + i];
    float4 v0 = *(const float4*)&x[(size_t)r0 * DIM + lane * 4];
    acc.x += v0.x; acc.y += v0.y; acc.z += v0.z; acc.w += v0.w;
  }
  const float S = DECAYF * (*ws_sum) + OMDF * (float)N_ROWS;
  const float scale = S / (S + (float)KCODES * EPSF);
  float ncs = cs[k] * DECAYF + (float)n * OMDF;
  if (lane == 0) out[CS_OFF + k] = ncs;
  float4 ea = *(const float4*)&embed_avg[(size_t)k * DIM + lane * 4];
  float4 nea;
  nea.x = ea.x * DECAYF + acc.x * OMDF;
  nea.y = ea.y * DECAYF + acc.y * OMDF;
  nea.z = ea.z * DECAYF + acc.z * OMDF;
  nea.w = ea.w * DECAYF + acc.w * OMDF;
  *(float4*)&out[EA_OFF + (size_t)k * DIM + lane * 4] = nea;
  float inv_sm = 1.0f / ((ncs + EPSF) * scale);
  float4 ne;
  ne.x = nea.x * inv_sm;
  ne.y = nea.y * inv_sm;
  ne.z = nea.z * inv_sm;
  ne.w = nea.w * inv_sm;
  *(float4*)&out[NE_OFF + (size_t)k * DIM + lane * 4] = ne;
}

// ---------------------------------------------------------------------------
__global__ void finish_q_kernel(const float* __restrict__ embed,
                                float* __restrict__ out) {
  const int lane = threadIdx.x & 63;
  const int wave = (blockIdx.x * blockDim.x + threadIdx.x) >> 6;  // 0..2047
  for (int row = wave; row < N_ROWS; row += 2048) {
    int k = (int)out[IND_OFF + row];
    float4 ev = *(const float4*)&embed[(size_t)k * DIM + lane * 4];
    *(float4*)&out[Q_OFF + (size_t)row * DIM + lane * 4] = ev;
  }
}

// ---------------------------------------------------------------------------
extern "C" void kernel_launch(void* const* d_in, const int* in_sizes, int n_in,
                              void* d_out, int out_size, void* d_ws, size_t ws_size,
                              hipStream_t stream) {
  const float* x = (const float*)d_in[0];
  const float* embed = (const float*)d_in[1];
  const float* cs = (const float*)d_in[2];
  const float* ea = (const float*)d_in[3];
  float* out = (float*)d_out;
  float* ws = (float*)d_ws;

  float* e2 = ws + WS_E2;
  int* cnt = (int*)(ws + WS_CNT);
  int* start = (int*)(ws + WS_START);
  int* cursor = (int*)(ws + WS_CUR);
  float* ws_sum = ws + WS_SUM;

  _Float16* Xp = (_Float16*)(out + Q_OFF);                          // 16 MB
  int* rowlist = (int*)(out + Q_OFF + 4194304);                     // Q dead half
  unsigned long long* gbest = (unsigned long long*)(out + EA_OFF);  // 256 KB
  _Float16* Ep = (_Float16*)(out + EA_OFF + 65536);                 // 4 MB

  prep_all_kernel<<<1280, 256, 0, stream>>>(x, embed, cs, Xp, Ep, out, ws);
  main_kernel<<<256, 512, 0, stream>>>(Xp, Ep, e2, gbest);
  decode_count_kernel<<<128, 256, 0, stream>>>(gbest, out, cnt);
  prefix_kernel<<<1, 1024, 0, stream>>>(cnt, start, cursor);
  scatter_rows_kernel<<<128, 256, 0, stream>>>(out, cursor, rowlist);
  bucket_final_kernel<<<2048, 256, 0, stream>>>(x, cs, ea, start, cnt,
                                                rowlist, out, ws_sum);
  finish_q_kernel<<<512, 256, 0, stream>>>(embed, out);
}

// Round 16
// 395.147 us; speedup vs baseline: 1.1658x; 1.1658x over previous
//
#include <hip/hip_runtime.h>

// Problem constants
#define N_ROWS 32768   // 8*4096
#define DIM    256
#define KCODES 8192
#define DECAYF 0.8f
#define OMDF   0.2f
#define EPSF   1e-5f

// d_out layout (float element offsets)
#define Q_OFF    0
#define IND_OFF  8388608
#define CS_OFF   8421376
#define EA_OFF   8429568
#define NE_OFF   10526720

// Scratch: Xp -> Q first half; rowlist -> Q second half; gbest -> EA head;
// Ep -> EA + 65536 floats. Same proven placement as r10-r14.

// ws layout: e2 f32[8192], cnt i32[8192], start i32[8192], cursor i32[8192],
// sum f32[1]
#define WS_E2    0
#define WS_CNT   8192
#define WS_START 16384
#define WS_CUR   24576
#define WS_SUM   40960

typedef _Float16 half8 __attribute__((ext_vector_type(8)));
typedef float floatx16 __attribute__((ext_vector_type(16)));

#define GLOAD16(g, l) __builtin_amdgcn_global_load_lds( \
    (const __attribute__((address_space(1))) void*)(g), \
    (__attribute__((address_space(3))) void*)(l), 16, 0, 0)

// ---------------------------------------------------------------------------
// prep_all (r10-verified, unchanged)
#define PREP_ROWS 32
__global__ void prep_all_kernel(const float* __restrict__ x,
                                const float* __restrict__ embed,
                                const float* __restrict__ cs,
                                _Float16* __restrict__ Xp,
                                _Float16* __restrict__ Ep,
                                float* __restrict__ out,
                                float* __restrict__ ws) {
  __shared__ __align__(16) _Float16 L[PREP_ROWS][264];
  __shared__ float red[4];
  const int t = threadIdx.x;
  const int bid = blockIdx.x;

  if (bid < 1024) {
    if (bid < 128) {
      unsigned long long* gbest = (unsigned long long*)(out + EA_OFF);
      gbest[bid * 256 + t] = 0ULL;
    } else if (bid < 160) {
      ((int*)(ws + WS_CNT))[(bid - 128) * 256 + t] = 0;
    }
    const int row0 = bid * PREP_ROWS;
    #pragma unroll
    for (int it = 0; it < 8; ++it) {
      int idx = it * 256 + t;
      int r = idx >> 6, q = idx & 63;
      float4 v = *(const float4*)&x[(size_t)(row0 + r) * DIM + q * 4];
      L[r][q * 4 + 0] = (_Float16)v.x;
      L[r][q * 4 + 1] = (_Float16)v.y;
      L[r][q * 4 + 2] = (_Float16)v.z;
      L[r][q * 4 + 3] = (_Float16)v.w;
    }
    __syncthreads();
    #pragma unroll
    for (int it = 0; it < 4; ++it) {
      int idx = it * 256 + t;
      int slot = idx >> 5, r = idx & 31;
      *(float4*)&Xp[((size_t)slot * N_ROWS + row0 + r) * 8] =
          *(const float4*)&L[r][slot * 8];
    }
  } else {
    const int row0 = (bid - 1024) * PREP_ROWS;
    float* e2 = ws + WS_E2;
    #pragma unroll
    for (int it = 0; it < 8; ++it) {
      int idx = it * 256 + t;
      int r = idx >> 6, q = idx & 63;
      float4 v = *(const float4*)&embed[(size_t)(row0 + r) * DIM + q * 4];
      L[r][q * 4 + 0] = (_Float16)v.x;
      L[r][q * 4 + 1] = (_Float16)v.y;
      L[r][q * 4 + 2] = (_Float16)v.z;
      L[r][q * 4 + 3] = (_Float16)v.w;
      float ssq = v.x * v.x + v.y * v.y + v.z * v.z + v.w * v.w;
      #pragma unroll
      for (int o = 32; o; o >>= 1) ssq += __shfl_xor(ssq, o);
      if ((t & 63) == 0) e2[row0 + r] = ssq;
    }
    if (bid == 1024) {
      float s = 0.0f;
      for (int j = t; j < KCODES; j += 256) s += cs[j];
      #pragma unroll
      for (int o = 32; o; o >>= 1) s += __shfl_xor(s, o);
      if ((t & 63) == 0) red[t >> 6] = s;
    }
    __syncthreads();
    if (bid == 1024 && t == 0)
      ws[WS_SUM] = red[0] + red[1] + red[2] + red[3];
    #pragma unroll
    for (int it = 0; it < 4; ++it) {
      int idx = it * 256 + t;
      int slot = idx >> 5, r = idx & 31;
      *(float4*)&Ep[((size_t)slot * KCODES + row0 + r) * 8] =
          *(const float4*)&L[r][slot * 8];
    }
  }
}

// ---------------------------------------------------------------------------
// Main MFMA kernel — 2-blocks/CU variant. Pure-hi GEMM K=256.
// Block 256 codes x 128 rows, 8 waves (4 code-groups x 2 row-groups),
// wave tile 64x64 -> acc[2][2] floatx16 = 64 VGPR (fits 128-reg budget for
// 4 waves/SIMD). K-step 16 (2 slots), 4-buffer LDS = 48KB -> 2 blocks/CU.
// A-waves stage 2 gloads/step (vmcnt(2)), B-waves 1 (vmcnt(1)).
// 512 persistent blocks, 16 row-tiles x 16 steps, per-tile argmax flush.
__global__ __launch_bounds__(512, 4) void main_kernel(
    const _Float16* __restrict__ Xp, const _Float16* __restrict__ Ep,
    const float* __restrict__ e2, unsigned long long* __restrict__ gbest) {
  __shared__ __align__(16) _Float16 As[4 * 2 * 256 * 8];  // [buf][slot][code][8] 32KB
  __shared__ __align__(16) _Float16 Bs[4 * 2 * 128 * 8];  // [buf][slot][row][8]  16KB
  __shared__ __align__(16) float e2s[256];                // 1KB

  const int t = threadIdx.x;
  const int w = t >> 6;
  const int lane = t & 63;
  const int l31 = lane & 31;
  const int h = lane >> 5;
  const int wm = w >> 1;   // code group 0..3 (64 codes each)
  const int wn = w & 1;    // row group 0..1 (64 rows each)

  // 512 blocks: xcd = bid&7 owns cb in [4*xcd,4*xcd+4); 16 row groups.
  const int bid = blockIdx.x;
  const int bi = bid >> 3;                   // 0..63
  const int cb = (bid & 7) * 4 + (bi >> 4);  // 0..31
  const int rg = bi & 15;                    // 0..15
  const int codes0 = cb * 256;
  const int rowbase = rg * 2048;             // 16 row-tiles of 128

  const bool isA = (w < 4);
  const int v4 = isA ? w : (w - 4);
  const int sl = v4 >> 1;   // k-slot 0..1 within step
  const int hf = v4 & 1;    // which half-panel

  // loop-invariant staging bases
  const _Float16* estage =
      Ep + ((size_t)sl * KCODES + codes0 + hf * 128 + lane) * 8;
  const _Float16* xstage =
      Xp + ((size_t)sl * N_ROWS + rowbase + hf * 64 + lane) * 8;
  _Float16* adst = &As[sl * 2048 + (hf * 128 + lane) * 8];
  _Float16* bdst = &Bs[sl * 1024 + (hf * 64 + lane) * 8];

  // stage flat step s: buf/stepk compile-time after unroll, rowT runtime
  auto stage = [&](int buf, int stepk, int rowT) {
    if (isA) {
      const _Float16* src = estage + (size_t)stepk * 2 * (KCODES * 8);
      _Float16* dst = adst + buf * 4096;
      GLOAD16(src, dst);
      GLOAD16(src + 512, dst + 512);
    } else {
      const _Float16* src =
          xstage + (size_t)stepk * 2 * (N_ROWS * 8) + (size_t)rowT * 1024;
      GLOAD16(src, bdst + buf * 2048);
    }
  };

  // prologue: e2 stash first (drains before staging vmcnt counts matter)
  if (t < 64) {
    float4 v = *(const float4*)&e2[codes0 + t * 4];
    *(float4*)&e2s[t * 4] = v;
  }
  __builtin_amdgcn_sched_barrier(0);
  stage(0, 0, 0);
  stage(1, 1, 0);
  if (isA) {
    asm volatile("s_waitcnt vmcnt(2)" ::: "memory");
  } else {
    asm volatile("s_waitcnt vmcnt(1)" ::: "memory");
  }
  asm volatile("s_waitcnt lgkmcnt(0)" ::: "memory");
  __builtin_amdgcn_s_barrier();
  __builtin_amdgcn_sched_barrier(0);

  floatx16 acc[2][2];

  #pragma unroll 1
  for (int tile = 0; tile < 16; ++tile) {
    // acc init = -0.5*e2 from LDS stash
    #pragma unroll
    for (int ct = 0; ct < 2; ++ct) {
      const int cl = wm * 64 + ct * 32 + 4 * h;
      #pragma unroll
      for (int rq = 0; rq < 4; ++rq) {
        float4 v = *(const float4*)&e2s[cl + rq * 8];
        acc[ct][0][rq * 4 + 0] = -0.5f * v.x;
        acc[ct][0][rq * 4 + 1] = -0.5f * v.y;
        acc[ct][0][rq * 4 + 2] = -0.5f * v.z;
        acc[ct][0][rq * 4 + 3] = -0.5f * v.w;
      }
      acc[ct][1] = acc[ct][0];
    }

    const bool lastTile = (tile == 15);
    #pragma unroll
    for (int i = 0; i < 16; ++i) {
      if (!(lastTile && i >= 14)) {
        const int ip = i + 2;
        stage(ip & 3, ip & 15, tile + (ip >> 4));
      }
      __builtin_amdgcn_sched_barrier(0);

      const int buf = i & 3;
      half8 a0 = *(const half8*)&As[buf * 4096 + h * 2048 +
                                    (wm * 64 + l31) * 8];
      half8 a1 = *(const half8*)&As[buf * 4096 + h * 2048 +
                                    (wm * 64 + 32 + l31) * 8];
      half8 b0 = *(const half8*)&Bs[buf * 2048 + h * 1024 +
                                    (wn * 64 + l31) * 8];
      half8 b1 = *(const half8*)&Bs[buf * 2048 + h * 1024 +
                                    (wn * 64 + 32 + l31) * 8];
      __builtin_amdgcn_s_setprio(1);
      acc[0][0] = __builtin_amdgcn_mfma_f32_32x32x16_f16(a0, b0, acc[0][0], 0, 0, 0);
      acc[0][1] = __builtin_amdgcn_mfma_f32_32x32x16_f16(a0, b1, acc[0][1], 0, 0, 0);
      acc[1][0] = __builtin_amdgcn_mfma_f32_32x32x16_f16(a1, b0, acc[1][0], 0, 0, 0);
      acc[1][1] = __builtin_amdgcn_mfma_f32_32x32x16_f16(a1, b1, acc[1][1], 0, 0, 0);
      __builtin_amdgcn_s_setprio(0);
      __builtin_amdgcn_sched_barrier(0);

      if (!(lastTile && i == 15)) {
        if (!(lastTile && i == 14)) {
          if (isA) {
            asm volatile("s_waitcnt vmcnt(2)" ::: "memory");
          } else {
            asm volatile("s_waitcnt vmcnt(1)" ::: "memory");
          }
        } else {
          asm volatile("s_waitcnt vmcnt(0)" ::: "memory");
        }
        __builtin_amdgcn_s_barrier();
        __builtin_amdgcn_sched_barrier(0);
      }
    }

    // tile epilogue: lane argmax -> h-butterfly -> direct atomicMax
    #pragma unroll
    for (int rt = 0; rt < 2; ++rt) {
      float best = -3.0e38f;
      int bidx = 0;
      #pragma unroll
      for (int ct = 0; ct < 2; ++ct) {
        const int cbase = codes0 + wm * 64 + ct * 32 + 4 * h;
        #pragma unroll
        for (int r = 0; r < 16; ++r) {
          const int code = cbase + (r & 3) + 8 * (r >> 2);
          float v = acc[ct][rt][r];
          if (v > best || (v == best && code < bidx)) { best = v; bidx = code; }
        }
      }
      unsigned u = __float_as_uint(best);
      u = (u & 0x80000000u) ? ~u : (u | 0x80000000u);
      unsigned long long p =
          ((unsigned long long)u << 32) | (unsigned)(8191 - bidx);
      unsigned long long op = (unsigned long long)__shfl_xor((long long)p, 32);
      if (op > p) p = op;
      if (h == 0)
        atomicMax(&gbest[rowbase + tile * 128 + wn * 64 + rt * 32 + l31], p);
    }
    if (!lastTile) {
      asm volatile("s_waitcnt vmcnt(0)" ::: "memory");  // re-prime rhythm
      __builtin_amdgcn_sched_barrier(0);
    }
  }
}

// ---------------------------------------------------------------------------
// decode_count: gbest -> IND + cnt histogram. Last reader of gbest.
__global__ void decode_count_kernel(const unsigned long long* __restrict__ gbest,
                                    float* __restrict__ out,
                                    int* __restrict__ cnt) {
  int r = blockIdx.x * blockDim.x + threadIdx.x;  // 32768 threads
  unsigned long long p = gbest[r];
  int k = 8191 - (int)(unsigned)(p & 0xFFFFFFFFull);
  out[IND_OFF + r] = (float)k;
  atomicAdd(&cnt[k], 1);
}

// ---------------------------------------------------------------------------
__global__ void prefix_kernel(const int* __restrict__ cnt,
                              int* __restrict__ start,
                              int* __restrict__ cursor) {
  __shared__ int part[1024];
  const int t = threadIdx.x;
  int loc[8];
  int s = 0;
  #pragma unroll
  for (int j = 0; j < 8; ++j) { loc[j] = cnt[t * 8 + j]; s += loc[j]; }
  part[t] = s;
  __syncthreads();
  for (int off = 1; off < 1024; off <<= 1) {
    int v = (t >= off) ? part[t - off] : 0;
    __syncthreads();
    part[t] += v;
    __syncthreads();
  }
  int base = part[t] - s;
  #pragma unroll
  for (int j = 0; j < 8; ++j) {
    start[t * 8 + j] = base;
    cursor[t * 8 + j] = base;
    base += loc[j];
  }
}

// ---------------------------------------------------------------------------
__global__ void scatter_rows_kernel(const float* __restrict__ out,
                                    int* __restrict__ cursor,
                                    int* __restrict__ rowlist) {
  int r = blockIdx.x * blockDim.x + threadIdx.x;  // 32768 threads
  int k = (int)out[IND_OFF + r];
  int pos = atomicAdd(&cursor[k], 1);
  rowlist[pos] = r;
}

// ---------------------------------------------------------------------------
__global__ void bucket_final_kernel(const float* __restrict__ x,
                                    const float* __restrict__ cs,
                                    const float* __restrict__ embed_avg,
                                    const int* __restrict__ start,
                                    const int* __restrict__ cnt,
                                    const int* __restrict__ rowlist,
                                    float* __restrict__ out,
                                    const float* __restrict__ ws_sum) {
  const int lane = threadIdx.x & 63;
  const int k = blockIdx.x * 4 + (threadIdx.x >> 6);
  const int s = start[k];
  const int n = cnt[k];
  float4 acc = make_float4(0.f, 0.f, 0.f, 0.f);
  int i = 0;
  for (; i + 2 <= n; i += 2) {
    int r0 = rowlist[s + i];
    int r1 = rowlist[s + i + 1];
    float4 v0 = *(const float4*)&x[(size_t)r0 * DIM + lane * 4];
    float4 v1 = *(const float4*)&x[(size_t)r1 * DIM + lane * 4];
    acc.x += v0.x + v1.x; acc.y += v0.y + v1.y;
    acc.z += v0.z + v1.z; acc.w += v0.w + v1.w;
  }
  if (i < n) {
    int r0 = rowlist[s + i];
    float4 v0 = *(const float4*)&x[(size_t)r0 * DIM + lane * 4];
    acc.x += v0.x; acc.y += v0.y; acc.z += v0.z; acc.w += v0.w;
  }
  const float S = DECAYF * (*ws_sum) + OMDF * (float)N_ROWS;
  const float scale = S / (S + (float)KCODES * EPSF);
  float ncs = cs[k] * DECAYF + (float)n * OMDF;
  if (lane == 0) out[CS_OFF + k] = ncs;
  float4 ea = *(const float4*)&embed_avg[(size_t)k * DIM + lane * 4];
  float4 nea;
  nea.x = ea.x * DECAYF + acc.x * OMDF;
  nea.y = ea.y * DECAYF + acc.y * OMDF;
  nea.z = ea.z * DECAYF + acc.z * OMDF;
  nea.w = ea.w * DECAYF + acc.w * OMDF;
  *(float4*)&out[EA_OFF + (size_t)k * DIM + lane * 4] = nea;
  float inv_sm = 1.0f / ((ncs + EPSF) * scale);
  float4 ne;
  ne.x = nea.x * inv_sm;
  ne.y = nea.y * inv_sm;
  ne.z = nea.z * inv_sm;
  ne.w = nea.w * inv_sm;
  *(float4*)&out[NE_OFF + (size_t)k * DIM + lane * 4] = ne;
}

// ---------------------------------------------------------------------------
__global__ void finish_q_kernel(const float* __restrict__ embed,
                                float* __restrict__ out) {
  const int lane = threadIdx.x & 63;
  const int wave = (blockIdx.x * blockDim.x + threadIdx.x) >> 6;  // 0..2047
  for (int row = wave; row < N_ROWS; row += 2048) {
    int k = (int)out[IND_OFF + row];
    float4 ev = *(const float4*)&embed[(size_t)k * DIM + lane * 4];
    *(float4*)&out[Q_OFF + (size_t)row * DIM + lane * 4] = ev;
  }
}

// ---------------------------------------------------------------------------
extern "C" void kernel_launch(void* const* d_in, const int* in_sizes, int n_in,
                              void* d_out, int out_size, void* d_ws, size_t ws_size,
                              hipStream_t stream) {
  const float* x = (const float*)d_in[0];
  const float* embed = (const float*)d_in[1];
  const float* cs = (const float*)d_in[2];
  const float* ea = (const float*)d_in[3];
  float* out = (float*)d_out;
  float* ws = (float*)d_ws;

  float* e2 = ws + WS_E2;
  int* cnt = (int*)(ws + WS_CNT);
  int* start = (int*)(ws + WS_START);
  int* cursor = (int*)(ws + WS_CUR);
  float* ws_sum = ws + WS_SUM;

  _Float16* Xp = (_Float16*)(out + Q_OFF);                          // 16 MB
  int* rowlist = (int*)(out + Q_OFF + 4194304);                     // Q dead half
  unsigned long long* gbest = (unsigned long long*)(out + EA_OFF);  // 256 KB
  _Float16* Ep = (_Float16*)(out + EA_OFF + 65536);                 // 4 MB

  prep_all_kernel<<<1280, 256, 0, stream>>>(x, embed, cs, Xp, Ep, out, ws);
  main_kernel<<<512, 512, 0, stream>>>(Xp, Ep, e2, gbest);
  decode_count_kernel<<<128, 256, 0, stream>>>(gbest, out, cnt);
  prefix_kernel<<<1, 1024, 0, stream>>>(cnt, start, cursor);
  scatter_rows_kernel<<<128, 256, 0, stream>>>(out, cursor, rowlist);
  bucket_final_kernel<<<2048, 256, 0, stream>>>(x, cs, ea, start, cnt,
                                                rowlist, out, ws_sum);
  finish_q_kernel<<<512, 256, 0, stream>>>(embed, out);
}